// Round 5
// baseline (156.131 us; speedup 1.0000x reference)
//
#include <hip/hip_runtime.h>

// ContrastiveLoss on MI355X (gfx950), B=8192, D=128, labels in [0,2048).
// loss = -(1/cnt) sum_{i: P_i>0} [ S_i/P_i - M - ln Z_i ]
//   Z_i = sum_{j != i} exp(sim_ij - M),  sim = E E^T / T,  M = 1/T (valid shift).
//   S_i = (e_i . g_{lab_i} - e_i . e_i) / T  with fp32 class sums g_c.
//   P_i = count[lab_i] - 1.
// R5: wave tile back to 64 rows (halves LDS-pipe time, the R4 bottleneck) with
//     __launch_bounds__(256,2) so the VGPR/AGPR split can't cause the R3 spill;
//     finalize2 merged into finalize1 via device atomics + last-block ticket.

#define BATCH 8192
#define DIMK  128
#define INV_T 14.285714285714286f
#define MSUB  14.285714285714286f
#define K1    20.609929155311264f   // INV_T * log2(e)
#define K2    20.609929155311264f   // MSUB  * log2(e)

typedef short bf16x8 __attribute__((ext_vector_type(8)));
typedef float f32x4  __attribute__((ext_vector_type(4)));

__device__ __forceinline__ unsigned short f2bf_rne(float f) {
    unsigned u = __float_as_uint(f);
    u += 0x7FFFu + ((u >> 16) & 1u);
    return (unsigned short)(u >> 16);
}
__device__ __forceinline__ float bf2f(unsigned short b) {
    return __uint_as_float(((unsigned)b) << 16);
}

// ---------------------------------------------------------------------------
// Prep: blocks [0,1024): fp32->bf16 cvt (4 elems/thread).
//       blocks [1024,1536): class sums, 1 class per wave, labels staged in LDS.
//       block 1535 also zeroes the finalize accumulators.
__global__ __launch_bounds__(256) void
prep_kernel(const float* __restrict__ emb, const int* __restrict__ labels,
            ushort* __restrict__ Ebf, float* __restrict__ gsum, int* __restrict__ gcnt,
            float* __restrict__ accS, unsigned* __restrict__ accC, unsigned* __restrict__ ticket) {
    if (blockIdx.x < 1024) {
        int i = blockIdx.x * 256 + threadIdx.x;
        float4 v = ((const float4*)emb)[i];
        ushort4 o;
        o.x = f2bf_rne(v.x); o.y = f2bf_rne(v.y);
        o.z = f2bf_rne(v.z); o.w = f2bf_rne(v.w);
        ((ushort4*)Ebf)[i] = o;
    } else {
        __shared__ int labs[BATCH];           // 32 KB
        const int tid = threadIdx.x;
        if (blockIdx.x == 1535 && tid == 0) { accS[0] = 0.f; accC[0] = 0u; ticket[0] = 0u; }
#pragma unroll
        for (int it = 0; it < 8; ++it)
            ((int4*)labs)[it * 256 + tid] = ((const int4*)labels)[it * 256 + tid];
        __syncthreads();

        const int lane = tid & 63;
        const int wid  = tid >> 6;
        const int c    = (blockIdx.x - 1024) * 4 + wid;   // class id [0,2048)
        float2 acc = {0.f, 0.f};
        int cnt = 0;
        int nl = labs[lane];
        for (int j0 = 0; j0 < BATCH; j0 += 64) {
            int cur = nl;
            int nidx = j0 + 64 < BATCH ? j0 + 64 : 0;
            nl = labs[nidx + lane];
            unsigned long long m = __ballot(cur == c);
            cnt += __popcll(m);
            while (m) {
                int j = __ffsll(m) - 1;
                m &= m - 1;
                float2 v = *(const float2*)(emb + (size_t)(j0 + j) * DIMK + lane * 2);
                acc.x += v.x; acc.y += v.y;
            }
        }
        *(float2*)(gsum + (size_t)c * DIMK + lane * 2) = acc;
        if (lane == 0) gcnt[c] = cnt;
    }
}

// ---------------------------------------------------------------------------
// Main: Z partials. Grid (32,64), block 256 (4 waves).
// Block = rows [bx*256,+256) x cols [by*128,+128). B-tile (128x128 bf16=32 KB)
// staged in LDS, XOR-swizzled (16B chunk c of col stored at c ^ (col&7)).
// Wave owns 64 rows (4 m-tiles, register a-frags), 8 n-tiles of 16 cols.
// launch_bounds(256,2): VGPR cap 256 so afrag[4][4]=64 regs can't trigger the
// 64/64 VGPR-AGPR-split spill seen in R3.
__global__ __launch_bounds__(256, 2) void
contrastive_main(const ushort* __restrict__ Ebf, float* __restrict__ zpart) {
    __shared__ __align__(16) ushort Bs[128 * DIMK];   // 32 KB
    const int tid  = threadIdx.x;
    const int lane = tid & 63;
    const int wid  = tid >> 6;
    const int quad = lane >> 4;
    const int l16  = lane & 15;
    const int row_base = blockIdx.x * 256 + wid * 64;
    const int col_base = blockIdx.y * 128;

    // Stage B-tile: 2048 16B-chunks; thread t, iter it handles flat chunk f.
#pragma unroll
    for (int it = 0; it < 8; ++it) {
        int f   = it * 256 + tid;
        int col = f >> 4;
        int c   = f & 15;
        uint4 v = *(const uint4*)(Ebf + (size_t)(col_base + col) * DIMK + c * 8);
        *(uint4*)&Bs[col * DIMK + ((c ^ (col & 7)) * 8)] = v;
    }

    // A-fragments for this wave's 64 rows (register-resident), from global.
    bf16x8 afrag[4][4];
#pragma unroll
    for (int mt = 0; mt < 4; ++mt)
#pragma unroll
        for (int kk = 0; kk < 4; ++kk)
            afrag[mt][kk] = *(const bf16x8*)(Ebf + (size_t)(row_base + mt * 16 + l16) * DIMK
                                             + kk * 32 + quad * 8);

    float zacc[16];
#pragma unroll
    for (int s = 0; s < 16; ++s) zacc[s] = 0.f;

    __syncthreads();

    for (int nt = 0; nt < 8; ++nt) {
        const int lcol = nt * 16 + l16;
        bf16x8 bfrag[4];
#pragma unroll
        for (int kk = 0; kk < 4; ++kk)
            bfrag[kk] = *(const bf16x8*)&Bs[lcol * DIMK + (((kk * 4 + quad) ^ (l16 & 7)) * 8)];

#pragma unroll
        for (int mt = 0; mt < 4; ++mt) {
            f32x4 c = {0.f, 0.f, 0.f, 0.f};
#pragma unroll
            for (int kk = 0; kk < 4; ++kk)
                c = __builtin_amdgcn_mfma_f32_16x16x32_bf16(afrag[mt][kk], bfrag[kk], c, 0, 0, 0);
#pragma unroll
            for (int r = 0; r < 4; ++r)
                zacc[mt * 4 + r] += __builtin_amdgcn_exp2f(__builtin_fmaf(c[r], K1, -K2));
        }
    }

    // Reduce each row-slot over the 16 lanes sharing the row; one store per row.
#pragma unroll
    for (int s = 0; s < 16; ++s) {
        float z = zacc[s];
#pragma unroll
        for (int m = 1; m <= 8; m <<= 1) z += __shfl_xor(z, m, 64);
        if (l16 == 0) {
            int row = row_base + (s >> 2) * 16 + quad * 4 + (s & 3);
            zpart[(size_t)blockIdx.y * BATCH + row] = z;
        }
    }
}

// ---------------------------------------------------------------------------
// Finalize: one wave per row. Grid 2048 x 256 (4 waves). Lane l: dims 2l,2l+1
// and zpart partial l. Block partial -> device atomics; last block writes out.
__global__ __launch_bounds__(256) void
finalize1(const float* __restrict__ emb, const ushort* __restrict__ Ebf,
          const int* __restrict__ labels, const float* __restrict__ gsum,
          const int* __restrict__ gcnt, const float* __restrict__ zpart,
          float* __restrict__ accS, unsigned* __restrict__ accC,
          unsigned* __restrict__ ticket, float* __restrict__ out) {
    __shared__ float sf[4];
    __shared__ int   si[4];
    const int lane = threadIdx.x & 63;
    const int wid  = threadIdx.x >> 6;
    const int r    = blockIdx.x * 4 + wid;
    const int lab  = labels[r];
    const int P    = gcnt[lab] - 1;

    float2 ev = *(const float2*)(emb  + (size_t)r   * DIMK + lane * 2);
    float2 gv = *(const float2*)(gsum + (size_t)lab * DIMK + lane * 2);
    unsigned bb = *(const unsigned*)(Ebf + (size_t)r * DIMK + lane * 2);
    float b0 = bf2f((unsigned short)(bb & 0xFFFF));
    float b1 = bf2f((unsigned short)(bb >> 16));

    float dotg = ev.x * gv.x + ev.y * gv.y;
    float ssd  = ev.x * ev.x + ev.y * ev.y;
    float sdbf = b0 * b0 + b1 * b1;
    float Z    = zpart[(size_t)lane * BATCH + r];

#pragma unroll
    for (int m = 1; m <= 32; m <<= 1) {
        dotg += __shfl_xor(dotg, m, 64);
        ssd  += __shfl_xor(ssd,  m, 64);
        sdbf += __shfl_xor(sdbf, m, 64);
        Z    += __shfl_xor(Z,    m, 64);
    }
    Z -= __builtin_amdgcn_exp2f(__builtin_fmaf(sdbf, K1, -K2));  // remove diagonal

    const bool has = (P > 0);
    float term = has ? ((dotg - ssd) * INV_T / (float)P - MSUB - __logf(Z)) : 0.f;
    if (lane == 0) { sf[wid] = term; si[wid] = has ? 1 : 0; }
    __syncthreads();
    if (threadIdx.x == 0) {
        atomicAdd(accS, sf[0] + sf[1] + sf[2] + sf[3]);
        atomicAdd(accC, (unsigned)(si[0] + si[1] + si[2] + si[3]));
        __threadfence();
        unsigned t = atomicAdd(ticket, 1u);
        if (t == 2047u) {
            float s = atomicAdd(accS, 0.f);          // coherent read-back
            unsigned c = atomicAdd(accC, 0u);
            out[0] = -s / (float)(c > 0u ? c : 1u);
        }
    }
}

extern "C" void kernel_launch(void* const* d_in, const int* in_sizes, int n_in,
                              void* d_out, int out_size, void* d_ws, size_t ws_size,
                              hipStream_t stream) {
    const float* emb  = (const float*)d_in[0];
    const int* labels = (const int*)d_in[1];
    float* out        = (float*)d_out;

    char* ws = (char*)d_ws;
    ushort*   Ebf    = (ushort*)ws;                          // 2 MB  (8192*128*2)
    float*    zpart  = (float*)(ws + (2u << 20));            // 2 MB  (64*8192*4)
    float*    gsum   = (float*)(ws + (4u << 20));            // 1 MB  (2048*128*4)
    int*      gcnt   = (int*)  (ws + (5u << 20));            // 8 KB
    float*    accS   = (float*)(ws + (5u << 20) + 8192);
    unsigned* accC   = (unsigned*)(ws + (5u << 20) + 8192 + 64);
    unsigned* ticket = (unsigned*)(ws + (5u << 20) + 8192 + 128);

    prep_kernel<<<1536, 256, 0, stream>>>(emb, labels, Ebf, gsum, gcnt, accS, accC, ticket);
    dim3 grid(32, 64);
    contrastive_main<<<grid, 256, 0, stream>>>(Ebf, zpart);
    finalize1<<<2048, 256, 0, stream>>>(emb, Ebf, labels, gsum, gcnt, zpart,
                                        accS, accC, ticket, out);
}

// Round 6
// 108.557 us; speedup vs baseline: 1.4382x; 1.4382x over previous
//
#include <hip/hip_runtime.h>

// ContrastiveLoss on MI355X (gfx950), B=8192, D=128, labels in [0,2048).
// loss = -(1/cnt) sum_{i: P_i>0} [ S_i/P_i - M - ln Z_i ]
//   Z_i = sum_{j != i} exp(sim_ij - M),  sim = E E^T / T,  M = 1/T (valid shift).
//   S_i = (e_i . g_{lab_i} - e_i . e_i) / T  with fp32 class sums g_c.
//   P_i = count[lab_i] - 1.
// R6: revert R5's same-address atomic finalize (56 us of serialized cross-XCD
//     atomics) to R4's contention-free bpart/bcnt arrays + 1-block reduce.
//     Main kernel unchanged from R5 (64-row waves, LDS B-tile, no spill).

#define BATCH 8192
#define DIMK  128
#define INV_T 14.285714285714286f
#define MSUB  14.285714285714286f
#define K1    20.609929155311264f   // INV_T * log2(e)
#define K2    20.609929155311264f   // MSUB  * log2(e)

typedef short bf16x8 __attribute__((ext_vector_type(8)));
typedef float f32x4  __attribute__((ext_vector_type(4)));

__device__ __forceinline__ unsigned short f2bf_rne(float f) {
    unsigned u = __float_as_uint(f);
    u += 0x7FFFu + ((u >> 16) & 1u);
    return (unsigned short)(u >> 16);
}
__device__ __forceinline__ float bf2f(unsigned short b) {
    return __uint_as_float(((unsigned)b) << 16);
}

// ---------------------------------------------------------------------------
// Prep: blocks [0,1024): fp32->bf16 cvt (4 elems/thread).
//       blocks [1024,1536): class sums, 1 class per wave, labels staged in LDS.
__global__ __launch_bounds__(256) void
prep_kernel(const float* __restrict__ emb, const int* __restrict__ labels,
            ushort* __restrict__ Ebf, float* __restrict__ gsum, int* __restrict__ gcnt) {
    if (blockIdx.x < 1024) {
        int i = blockIdx.x * 256 + threadIdx.x;
        float4 v = ((const float4*)emb)[i];
        ushort4 o;
        o.x = f2bf_rne(v.x); o.y = f2bf_rne(v.y);
        o.z = f2bf_rne(v.z); o.w = f2bf_rne(v.w);
        ((ushort4*)Ebf)[i] = o;
    } else {
        __shared__ int labs[BATCH];           // 32 KB
        const int tid = threadIdx.x;
#pragma unroll
        for (int it = 0; it < 8; ++it)
            ((int4*)labs)[it * 256 + tid] = ((const int4*)labels)[it * 256 + tid];
        __syncthreads();

        const int lane = tid & 63;
        const int wid  = tid >> 6;
        const int c    = (blockIdx.x - 1024) * 4 + wid;   // class id [0,2048)
        float2 acc = {0.f, 0.f};
        int cnt = 0;
        int nl = labs[lane];
        for (int j0 = 0; j0 < BATCH; j0 += 64) {
            int cur = nl;
            int nidx = j0 + 64 < BATCH ? j0 + 64 : 0;
            nl = labs[nidx + lane];
            unsigned long long m = __ballot(cur == c);
            cnt += __popcll(m);
            while (m) {
                int j = __ffsll(m) - 1;
                m &= m - 1;
                float2 v = *(const float2*)(emb + (size_t)(j0 + j) * DIMK + lane * 2);
                acc.x += v.x; acc.y += v.y;
            }
        }
        *(float2*)(gsum + (size_t)c * DIMK + lane * 2) = acc;
        if (lane == 0) gcnt[c] = cnt;
    }
}

// ---------------------------------------------------------------------------
// Main: Z partials. Grid (32,64), block 256 (4 waves).
// Block = rows [bx*256,+256) x cols [by*128,+128). B-tile (128x128 bf16=32 KB)
// staged in LDS, XOR-swizzled (16B chunk c of col stored at c ^ (col&7)).
// Wave owns 64 rows (4 m-tiles, register a-frags), 8 n-tiles of 16 cols.
__global__ __launch_bounds__(256, 2) void
contrastive_main(const ushort* __restrict__ Ebf, float* __restrict__ zpart) {
    __shared__ __align__(16) ushort Bs[128 * DIMK];   // 32 KB
    const int tid  = threadIdx.x;
    const int lane = tid & 63;
    const int wid  = tid >> 6;
    const int quad = lane >> 4;
    const int l16  = lane & 15;
    const int row_base = blockIdx.x * 256 + wid * 64;
    const int col_base = blockIdx.y * 128;

    // Stage B-tile: 2048 16B-chunks; thread t, iter it handles flat chunk f.
#pragma unroll
    for (int it = 0; it < 8; ++it) {
        int f   = it * 256 + tid;
        int col = f >> 4;
        int c   = f & 15;
        uint4 v = *(const uint4*)(Ebf + (size_t)(col_base + col) * DIMK + c * 8);
        *(uint4*)&Bs[col * DIMK + ((c ^ (col & 7)) * 8)] = v;
    }

    // A-fragments for this wave's 64 rows (register-resident), from global.
    bf16x8 afrag[4][4];
#pragma unroll
    for (int mt = 0; mt < 4; ++mt)
#pragma unroll
        for (int kk = 0; kk < 4; ++kk)
            afrag[mt][kk] = *(const bf16x8*)(Ebf + (size_t)(row_base + mt * 16 + l16) * DIMK
                                             + kk * 32 + quad * 8);

    float zacc[16];
#pragma unroll
    for (int s = 0; s < 16; ++s) zacc[s] = 0.f;

    __syncthreads();

    for (int nt = 0; nt < 8; ++nt) {
        const int lcol = nt * 16 + l16;
        bf16x8 bfrag[4];
#pragma unroll
        for (int kk = 0; kk < 4; ++kk)
            bfrag[kk] = *(const bf16x8*)&Bs[lcol * DIMK + (((kk * 4 + quad) ^ (l16 & 7)) * 8)];

#pragma unroll
        for (int mt = 0; mt < 4; ++mt) {
            f32x4 c = {0.f, 0.f, 0.f, 0.f};
#pragma unroll
            for (int kk = 0; kk < 4; ++kk)
                c = __builtin_amdgcn_mfma_f32_16x16x32_bf16(afrag[mt][kk], bfrag[kk], c, 0, 0, 0);
#pragma unroll
            for (int r = 0; r < 4; ++r)
                zacc[mt * 4 + r] += __builtin_amdgcn_exp2f(__builtin_fmaf(c[r], K1, -K2));
        }
    }

    // Reduce each row-slot over the 16 lanes sharing the row; one store per row.
#pragma unroll
    for (int s = 0; s < 16; ++s) {
        float z = zacc[s];
#pragma unroll
        for (int m = 1; m <= 8; m <<= 1) z += __shfl_xor(z, m, 64);
        if (l16 == 0) {
            int row = row_base + (s >> 2) * 16 + quad * 4 + (s & 3);
            zpart[(size_t)blockIdx.y * BATCH + row] = z;
        }
    }
}

// ---------------------------------------------------------------------------
// Finalize 1: one wave per row. Grid 2048 x 256 (4 waves). Lane l: dims 2l,2l+1
// and zpart partial l. Block partial -> bpart/bcnt[2048] (no contention).
__global__ __launch_bounds__(256) void
finalize1(const float* __restrict__ emb, const ushort* __restrict__ Ebf,
          const int* __restrict__ labels, const float* __restrict__ gsum,
          const int* __restrict__ gcnt, const float* __restrict__ zpart,
          float* __restrict__ bpart, int* __restrict__ bcnt) {
    __shared__ float sf[4];
    __shared__ int   si[4];
    const int lane = threadIdx.x & 63;
    const int wid  = threadIdx.x >> 6;
    const int r    = blockIdx.x * 4 + wid;
    const int lab  = labels[r];
    const int P    = gcnt[lab] - 1;

    float2 ev = *(const float2*)(emb  + (size_t)r   * DIMK + lane * 2);
    float2 gv = *(const float2*)(gsum + (size_t)lab * DIMK + lane * 2);
    unsigned bb = *(const unsigned*)(Ebf + (size_t)r * DIMK + lane * 2);
    float b0 = bf2f((unsigned short)(bb & 0xFFFF));
    float b1 = bf2f((unsigned short)(bb >> 16));

    float dotg = ev.x * gv.x + ev.y * gv.y;
    float ssd  = ev.x * ev.x + ev.y * ev.y;
    float sdbf = b0 * b0 + b1 * b1;
    float Z    = zpart[(size_t)lane * BATCH + r];

#pragma unroll
    for (int m = 1; m <= 32; m <<= 1) {
        dotg += __shfl_xor(dotg, m, 64);
        ssd  += __shfl_xor(ssd,  m, 64);
        sdbf += __shfl_xor(sdbf, m, 64);
        Z    += __shfl_xor(Z,    m, 64);
    }
    Z -= __builtin_amdgcn_exp2f(__builtin_fmaf(sdbf, K1, -K2));  // remove diagonal

    const bool has = (P > 0);
    float term = has ? ((dotg - ssd) * INV_T / (float)P - MSUB - __logf(Z)) : 0.f;
    if (lane == 0) { sf[wid] = term; si[wid] = has ? 1 : 0; }
    __syncthreads();
    if (threadIdx.x == 0) {
        bpart[blockIdx.x] = sf[0] + sf[1] + sf[2] + sf[3];
        bcnt [blockIdx.x] = si[0] + si[1] + si[2] + si[3];
    }
}

// ---------------------------------------------------------------------------
// Finalize 2: reduce 2048 block partials -> scalar loss. 1 block x 256.
__global__ __launch_bounds__(256) void
finalize2(const float* __restrict__ bpart, const int* __restrict__ bcnt,
          float* __restrict__ out) {
    __shared__ float sf[4];
    __shared__ int   si[4];
    const int t = threadIdx.x;
    float v = 0.f; int c = 0;
#pragma unroll
    for (int k = 0; k < 8; ++k) {
        v += bpart[t + k * 256];
        c += bcnt [t + k * 256];
    }
#pragma unroll
    for (int m = 1; m <= 32; m <<= 1) {
        v += __shfl_xor(v, m, 64);
        c += __shfl_xor(c, m, 64);
    }
    if ((t & 63) == 0) { sf[t >> 6] = v; si[t >> 6] = c; }
    __syncthreads();
    if (t == 0) {
        float tot = sf[0] + sf[1] + sf[2] + sf[3];
        int cc = si[0] + si[1] + si[2] + si[3];
        out[0] = -tot / (float)(cc > 0 ? cc : 1);
    }
}

extern "C" void kernel_launch(void* const* d_in, const int* in_sizes, int n_in,
                              void* d_out, int out_size, void* d_ws, size_t ws_size,
                              hipStream_t stream) {
    const float* emb  = (const float*)d_in[0];
    const int* labels = (const int*)d_in[1];
    float* out        = (float*)d_out;

    char* ws = (char*)d_ws;
    ushort* Ebf   = (ushort*)ws;                         // 2 MB  (8192*128*2)
    float*  zpart = (float*)(ws + (2u << 20));           // 2 MB  (64*8192*4)
    float*  gsum  = (float*)(ws + (4u << 20));           // 1 MB  (2048*128*4)
    int*    gcnt  = (int*)  (ws + (5u << 20));           // 8 KB
    float*  bpart = (float*)(ws + (5u << 20) + 8192);    // 8 KB
    int*    bcnt  = (int*)  (ws + (5u << 20) + 16384);   // 8 KB

    prep_kernel<<<1536, 256, 0, stream>>>(emb, labels, Ebf, gsum, gcnt);
    dim3 grid(32, 64);
    contrastive_main<<<grid, 256, 0, stream>>>(Ebf, zpart);
    finalize1<<<2048, 256, 0, stream>>>(emb, Ebf, labels, gsum, gcnt, zpart, bpart, bcnt);
    finalize2<<<1, 256, 0, stream>>>(bpart, bcnt, out);
}